// Round 1
// baseline (602.071 us; speedup 1.0000x reference)
//
#include <hip/hip_runtime.h>

#define N_NODES 50000
#define N_EDGES 600000
#define DH 128
#define DOUT 64
#define NG 64
#define SLOPE 0.2f

__device__ __forceinline__ float leaky(float v){ return v > 0.f ? v : v*SLOPE; }

// ---------------- CSR build (by dst), self-loops handled implicitly ----------------
__global__ void k_hist(const int* __restrict__ dst, int* __restrict__ counts){
  int e = blockIdx.x*256 + threadIdx.x;
  if (e < N_EDGES) atomicAdd(&counts[dst[e]], 1);
}

__global__ void k_bscan1(const int* __restrict__ counts, int* __restrict__ bsum){
  __shared__ int sb[256];
  int base = blockIdx.x*2048;
  int t = threadIdx.x;
  int s = 0;
  #pragma unroll
  for (int j=0;j<8;j++){ int i = base + t*8 + j; if (i < N_NODES) s += counts[i]; }
  sb[t]=s; __syncthreads();
  for (int off=128; off>0; off>>=1){ if (t<off) sb[t]+=sb[t+off]; __syncthreads(); }
  if (t==0) bsum[blockIdx.x]=sb[0];
}

__global__ void k_bscan2(const int* __restrict__ bsum, int* __restrict__ boff,
                         int* __restrict__ row_ptr, int nb){
  if (threadIdx.x==0 && blockIdx.x==0){
    int run=0;
    for (int b=0;b<nb;b++){ boff[b]=run; run+=bsum[b]; }
    row_ptr[N_NODES]=run;   // == N_EDGES
  }
}

__global__ void k_bscan3(const int* __restrict__ counts, const int* __restrict__ boff,
                         int* __restrict__ row_ptr, int* __restrict__ cursor){
  __shared__ int sb[256];
  int base = blockIdx.x*2048;
  int t = threadIdx.x;
  int c[8]; int s=0;
  #pragma unroll
  for (int j=0;j<8;j++){ int i = base+t*8+j; c[j] = (i<N_NODES)? counts[i]:0; s += c[j]; }
  sb[t]=s; __syncthreads();
  for (int off=1; off<256; off<<=1){
    int v = (t>=off)? sb[t-off] : 0;
    __syncthreads();
    sb[t]+=v;
    __syncthreads();
  }
  int run = sb[t]-s + boff[blockIdx.x];   // exclusive prefix for this thread's chunk
  #pragma unroll
  for (int j=0;j<8;j++){
    int i = base+t*8+j;
    if (i<N_NODES){ row_ptr[i]=run; cursor[i]=run; run+=c[j]; }
  }
}

__global__ void k_scatter(const int* __restrict__ esrc, const int* __restrict__ edst,
                          int* __restrict__ cursor, int* __restrict__ col_src){
  int e = blockIdx.x*256 + threadIdx.x;
  if (e < N_EDGES){
    int d = edst[e];
    int p = atomicAdd(&cursor[d],1);
    col_src[p] = esrc[e];
  }
}

// ---------------- [nrows,128] x [128,128] GEMM, fused attention-vector dots ----------------
__global__ __launch_bounds__(256)
void k_linear(const float* __restrict__ X, const float* __restrict__ W,
              const float* __restrict__ bias,
              const float* __restrict__ avs, const float* __restrict__ avd,
              float* __restrict__ OUT, float* __restrict__ es, float* __restrict__ ed,
              int nrows){
  __shared__ float xs[32*128];
  int R0 = blockIdx.x*32;
  int tid = threadIdx.x;
  for (int f = tid; f < 1024; f += 256){          // 32 rows * 32 float4
    int r = f >> 5;
    float4 v = make_float4(0.f,0.f,0.f,0.f);
    if (R0 + r < nrows) v = ((const float4*)(X + (size_t)(R0+r)*DH))[f & 31];
    ((float4*)xs)[f] = v;
  }
  __syncthreads();
  int wave = tid >> 6, lane = tid & 63;
  int c0 = lane, c1 = lane + 64;
  float acc[8][2];
  #pragma unroll
  for (int r=0;r<8;r++){ acc[r][0]=0.f; acc[r][1]=0.f; }
  const float* xb = xs + wave*8*DH;
  for (int k4 = 0; k4 < 32; k4++){
    int k = k4*4;
    float w00 = W[(k+0)*DH+c0], w01=W[(k+1)*DH+c0], w02=W[(k+2)*DH+c0], w03=W[(k+3)*DH+c0];
    float w10 = W[(k+0)*DH+c1], w11=W[(k+1)*DH+c1], w12=W[(k+2)*DH+c1], w13=W[(k+3)*DH+c1];
    #pragma unroll
    for (int r=0;r<8;r++){
      float4 xv = *(const float4*)(xb + r*DH + k);
      acc[r][0] = fmaf(xv.x,w00, fmaf(xv.y,w01, fmaf(xv.z,w02, fmaf(xv.w,w03, acc[r][0]))));
      acc[r][1] = fmaf(xv.x,w10, fmaf(xv.y,w11, fmaf(xv.z,w12, fmaf(xv.w,w13, acc[r][1]))));
    }
  }
  float b0 = bias ? bias[c0] : 0.f;
  float b1v = bias ? bias[c1] : 0.f;
  float as0=0.f, as1=0.f, ad0=0.f, ad1=0.f;
  if (avs){ as0=avs[c0]; as1=avs[c1]; ad0=avd[c0]; ad1=avd[c1]; }
  #pragma unroll
  for (int r=0;r<8;r++){
    int row = R0 + wave*8 + r;
    if (row >= nrows) break;
    float o0 = acc[r][0] + b0, o1 = acc[r][1] + b1v;
    OUT[(size_t)row*DH + c0] = o0;
    OUT[(size_t)row*DH + c1] = o1;
    if (avs){
      float ps = o0*as0 + o1*as1;
      float pd = o0*ad0 + o1*ad1;
      #pragma unroll
      for (int off=32; off>0; off>>=1){
        ps += __shfl_xor(ps, off, 64);
        pd += __shfl_xor(pd, off, 64);
      }
      if (lane==0){ es[row]=ps; ed[row]=pd; }
    }
  }
}

// ---------------- GAT aggregation: one wave per dst node; in-place residual ----------------
__global__ __launch_bounds__(256)
void k_gat_agg(const float* __restrict__ hp, const float* __restrict__ es,
               const float* __restrict__ ed, const int* __restrict__ row_ptr,
               const int* __restrict__ col_src, const float* __restrict__ bg,
               float* __restrict__ h){
  int i = blockIdx.x*4 + (threadIdx.x >> 6);
  if (i >= N_NODES) return;
  int lane = threadIdx.x & 63;
  int start = row_ptr[i], end = row_ptr[i+1];
  float edi = ed[i];
  float eself = leaky(es[i] + edi);
  float m = eself;
  for (int j = start + lane; j < end; j += 64){
    m = fmaxf(m, leaky(es[col_src[j]] + edi));
  }
  #pragma unroll
  for (int off=32; off>0; off>>=1) m = fmaxf(m, __shfl_xor(m, off, 64));
  float w = __expf(eself - m);
  float z = w;
  int c0 = lane, c1 = lane+64;
  float acc0 = w * hp[(size_t)i*DH + c0];
  float acc1 = w * hp[(size_t)i*DH + c1];
  for (int j = start; j < end; j++){
    int s = col_src[j];                          // wave-uniform broadcast
    float wj = __expf(leaky(es[s] + edi) - m);   // same in all lanes
    z += wj;
    acc0 = fmaf(wj, hp[(size_t)s*DH + c0], acc0);
    acc1 = fmaf(wj, hp[(size_t)s*DH + c1], acc1);
  }
  float inv = 1.f / z;
  float r0 = acc0*inv + bg[c0];
  float r1 = acc1*inv + bg[c1];
  size_t o = (size_t)i*DH;
  h[o+c0] = (r0 > 0.f ? r0 : 0.f) + h[o+c0];
  h[o+c1] = (r1 > 0.f ? r1 : 0.f) + h[o+c1];
}

// ---------------- global_add_pool + final linear ----------------
__global__ void k_pool(const float* __restrict__ h, const int* __restrict__ batch,
                       float* __restrict__ pooled){
  int gid = blockIdx.x*256 + threadIdx.x;
  int node = gid >> 6, lane = gid & 63;
  if (node >= N_NODES) return;
  int b = batch[node];
  atomicAdd(&pooled[b*DH + lane],      h[(size_t)node*DH + lane]);
  atomicAdd(&pooled[b*DH + lane + 64], h[(size_t)node*DH + lane + 64]);
}

__global__ void k_final(const float* __restrict__ pooled, const float* __restrict__ W2,
                        const float* __restrict__ b2, float* __restrict__ out){
  int gid = blockIdx.x*256 + threadIdx.x;    // 64*64 = 4096 outputs
  if (gid >= NG*DOUT) return;
  int r = gid >> 6, c = gid & 63;
  float acc = b2[c];
  #pragma unroll 4
  for (int k=0;k<DH;k++) acc = fmaf(pooled[r*DH+k], W2[k*DOUT+c], acc);
  out[(size_t)r*DOUT + c] = acc;
}

extern "C" void kernel_launch(void* const* d_in, const int* in_sizes, int n_in,
                              void* d_out, int out_size, void* d_ws, size_t ws_size,
                              hipStream_t stream){
  const float* x     = (const float*)d_in[0];
  const int*   ei    = (const int*)d_in[1];     // [2,E] flat; row0=src, row1=dst
  const int*   batch = (const int*)d_in[2];
  const float* W1    = (const float*)d_in[3];
  const float* b1    = (const float*)d_in[4];
  const float* Wg    = (const float*)d_in[5];   // [3,128,128]
  const float* avs   = (const float*)d_in[6];   // [3,128]
  const float* avd   = (const float*)d_in[7];
  const float* bgv   = (const float*)d_in[8];
  const float* W2    = (const float*)d_in[9];
  const float* b2    = (const float*)d_in[10];
  float* out = (float*)d_out;

  float* h      = (float*)d_ws;                       // N*128
  float* hp     = h  + (size_t)N_NODES*DH;            // N*128
  float* es     = hp + (size_t)N_NODES*DH;            // N
  float* ed     = es + N_NODES;                       // N
  float* pooled = ed + N_NODES;                       // 64*128
  int* counts   = (int*)(pooled + NG*DH);             // N
  int* row_ptr  = counts + N_NODES;                   // N+1
  int* cursor   = row_ptr + N_NODES + 1;              // N
  int* col_src  = cursor + N_NODES;                   // E
  int* bsum     = col_src + N_EDGES;                  // 64
  int* boff     = bsum + 64;                          // 64

  const int* esrc = ei;
  const int* edst = ei + N_EDGES;

  hipMemsetAsync(counts, 0, N_NODES*sizeof(int), stream);
  hipMemsetAsync(pooled, 0, NG*DH*sizeof(float), stream);

  k_hist<<<(N_EDGES+255)/256, 256, 0, stream>>>(edst, counts);
  int nb = (N_NODES + 2047)/2048;   // 25
  k_bscan1<<<nb,256,0,stream>>>(counts, bsum);
  k_bscan2<<<1,64,0,stream>>>(bsum, boff, row_ptr, nb);
  k_bscan3<<<nb,256,0,stream>>>(counts, boff, row_ptr, cursor);
  k_scatter<<<(N_EDGES+255)/256,256,0,stream>>>(esrc, edst, cursor, col_src);

  k_linear<<<(N_NODES+31)/32, 256, 0, stream>>>(x, W1, b1, nullptr, nullptr,
                                                h, nullptr, nullptr, N_NODES);
  for (int l=0;l<3;l++){
    k_linear<<<(N_NODES+31)/32, 256, 0, stream>>>(h, Wg + (size_t)l*DH*DH, nullptr,
                 avs + l*DH, avd + l*DH, hp, es, ed, N_NODES);
    k_gat_agg<<<(N_NODES+3)/4, 256, 0, stream>>>(hp, es, ed, row_ptr, col_src,
                                                 bgv + l*DH, h);
  }
  k_pool<<<(N_NODES*64+255)/256, 256, 0, stream>>>(h, batch, pooled);
  k_final<<<(NG*DOUT+255)/256, 256, 0, stream>>>(pooled, W2, b2, out);
}

// Round 2
// 355.605 us; speedup vs baseline: 1.6931x; 1.6931x over previous
//
#include <hip/hip_runtime.h>

#define N_NODES 50000
#define N_EDGES 600000
#define DH 128
#define DOUT 64
#define NG 64
#define SLOPE 0.2f

using short8  = __attribute__((ext_vector_type(8))) short;
using floatx4 = __attribute__((ext_vector_type(4))) float;

__device__ __forceinline__ float leaky(float v){ return v > 0.f ? v : v*SLOPE; }
__device__ __forceinline__ unsigned f2bf(float x){
  unsigned u = __float_as_uint(x);
  return (u + 0x7fffu + ((u>>16)&1u)) >> 16;          // RNE bf16
}
__device__ __forceinline__ float bf_lo(unsigned u){ return __uint_as_float(u<<16); }
__device__ __forceinline__ float bf_hi(unsigned u){ return __uint_as_float(u & 0xffff0000u); }

// ---------------- CSR build (by dst), self-loops handled implicitly ----------------
__global__ void k_hist(const int* __restrict__ dst, int* __restrict__ counts){
  int e = blockIdx.x*256 + threadIdx.x;
  if (e < N_EDGES) atomicAdd(&counts[dst[e]], 1);
}

__global__ void k_bscan1(const int* __restrict__ counts, int* __restrict__ bsum){
  __shared__ int sb[256];
  int base = blockIdx.x*2048;
  int t = threadIdx.x;
  int s = 0;
  #pragma unroll
  for (int j=0;j<8;j++){ int i = base + t*8 + j; if (i < N_NODES) s += counts[i]; }
  sb[t]=s; __syncthreads();
  for (int off=128; off>0; off>>=1){ if (t<off) sb[t]+=sb[t+off]; __syncthreads(); }
  if (t==0) bsum[blockIdx.x]=sb[0];
}

__global__ void k_bscan2(const int* __restrict__ bsum, int* __restrict__ boff,
                         int* __restrict__ row_ptr, int nb){
  if (threadIdx.x==0 && blockIdx.x==0){
    int run=0;
    for (int b=0;b<nb;b++){ boff[b]=run; run+=bsum[b]; }
    row_ptr[N_NODES]=run;
  }
}

__global__ void k_bscan3(const int* __restrict__ counts, const int* __restrict__ boff,
                         int* __restrict__ row_ptr, int* __restrict__ cursor){
  __shared__ int sb[256];
  int base = blockIdx.x*2048;
  int t = threadIdx.x;
  int c[8]; int s=0;
  #pragma unroll
  for (int j=0;j<8;j++){ int i = base+t*8+j; c[j] = (i<N_NODES)? counts[i]:0; s += c[j]; }
  sb[t]=s; __syncthreads();
  for (int off=1; off<256; off<<=1){
    int v = (t>=off)? sb[t-off] : 0;
    __syncthreads();
    sb[t]+=v;
    __syncthreads();
  }
  int run = sb[t]-s + boff[blockIdx.x];
  #pragma unroll
  for (int j=0;j<8;j++){
    int i = base+t*8+j;
    if (i<N_NODES){ row_ptr[i]=run; cursor[i]=run; run+=c[j]; }
  }
}

__global__ void k_scatter(const int* __restrict__ esrc, const int* __restrict__ edst,
                          int* __restrict__ cursor, int* __restrict__ col_src){
  int e = blockIdx.x*256 + threadIdx.x;
  if (e < N_EDGES){
    int d = edst[e];
    int p = atomicAdd(&cursor[d],1);
    col_src[p] = esrc[e];
  }
}

// ---------------- weight prep: W[k][n] fp32 -> Wt[n][k] bf16, 4 matrices ----------------
__global__ void k_prep(const float* __restrict__ W1, const float* __restrict__ Wg,
                       unsigned short* __restrict__ Wt){
  int idx = blockIdx.x*256 + threadIdx.x;      // 4*16384
  if (idx >= 4*16384) return;
  int mi = idx >> 14, r = idx & 16383;
  int k = r >> 7, n = r & 127;                 // coalesced read along n
  const float* src = (mi==0) ? W1 : (Wg + (size_t)(mi-1)*16384);
  float v = src[k*128 + n];
  Wt[(size_t)mi*16384 + (size_t)n*128 + k] = (unsigned short)f2bf(v);
}

// ---------------- fp32 -> bf16 cast (x) ----------------
__global__ void k_cast(const float* __restrict__ in, uint2* __restrict__ out){
  int idx = blockIdx.x*256 + threadIdx.x;      // N*128/4 = 1.6M
  if (idx >= N_NODES*32) return;
  float4 v = ((const float4*)in)[idx];
  uint2 o;
  o.x = f2bf(v.x) | (f2bf(v.y)<<16);
  o.y = f2bf(v.z) | (f2bf(v.w)<<16);
  out[idx] = o;
}

// ---------------- MFMA GEMM: [nrows,128](bf16) x [128,128] -> out, fused es/ed ----------------
// A row-major bf16. Wt: [n][k] bf16 (one matrix, 16384 elems). Layouts (gfx950 verified):
// A frag: A[m=lane&15][k=quad*8+j]; B frag: B[k=quad*8+j][n=lane&15]; C/D: col=lane&15,row=quad*4+reg
__global__ __launch_bounds__(256)
void k_linear_mfma(const unsigned short* __restrict__ A,
                   const unsigned short* __restrict__ Wt,
                   const float* __restrict__ bias,
                   const float* __restrict__ avs, const float* __restrict__ avd,
                   float* __restrict__ outF, unsigned short* __restrict__ outB,
                   float* __restrict__ es, float* __restrict__ ed, int nrows){
  __shared__ unsigned short wlds[128*136];     // +8 pad: conflict-free b128
  int tid = threadIdx.x;
  // stage Wt into LDS (32 KB, 16B vector loads)
  #pragma unroll
  for (int i=0;i<8;i++){
    int flat = i*2048 + tid*8;
    int n = flat >> 7, kb = flat & 127;
    *(short8*)&wlds[n*136 + kb] = *(const short8*)(Wt + flat);
  }
  __syncthreads();

  int wid = tid >> 6, lane = tid & 63;
  int l15 = lane & 15, quad = lane >> 4;
  int R0 = blockIdx.x*64 + wid*16;
  int arow = R0 + l15; if (arow >= nrows) arow = nrows-1;
  const unsigned short* Ap = A + (size_t)arow*128 + quad*8;

  floatx4 acc[8];
  #pragma unroll
  for (int nt=0;nt<8;nt++){ acc[nt][0]=0.f; acc[nt][1]=0.f; acc[nt][2]=0.f; acc[nt][3]=0.f; }

  #pragma unroll
  for (int k0=0;k0<128;k0+=32){
    short8 a = *(const short8*)(Ap + k0);
    const unsigned short* bp = &wlds[l15*136 + quad*8 + k0];
    #pragma unroll
    for (int nt=0;nt<8;nt++){
      short8 b = *(const short8*)(bp + nt*16*136);
      acc[nt] = __builtin_amdgcn_mfma_f32_16x16x32_bf16(a, b, acc[nt], 0,0,0);
    }
  }

  float bs[8], as[8], ad[8];
  #pragma unroll
  for (int nt=0;nt<8;nt++){
    int c = nt*16 + l15;
    bs[nt] = bias ? bias[c] : 0.f;
    as[nt] = avs ? avs[c] : 0.f;
    ad[nt] = avd ? avd[c] : 0.f;
  }
  #pragma unroll
  for (int reg=0; reg<4; reg++){
    int r = R0 + quad*4 + reg;
    if (r < nrows){
      float ps = 0.f, pd = 0.f;
      #pragma unroll
      for (int nt=0;nt<8;nt++){
        float v = acc[nt][reg] + bs[nt];
        int c = nt*16 + l15;
        if (outF) outF[(size_t)r*128 + c] = v;
        if (outB) outB[(size_t)r*128 + c] = (unsigned short)f2bf(v);
        ps = fmaf(v, as[nt], ps);
        pd = fmaf(v, ad[nt], pd);
      }
      if (es){
        #pragma unroll
        for (int off=1; off<16; off<<=1){
          ps += __shfl_xor(ps, off, 64);
          pd += __shfl_xor(pd, off, 64);
        }
        if (l15==0){ es[r]=ps; ed[r]=pd; }
      }
    }
  }
}

// ---------------- GAT aggregation: wave/node, bf16 gather, online softmax, x4 unroll ----------
__global__ __launch_bounds__(256)
void k_gat_agg(const unsigned* __restrict__ hp2, const float* __restrict__ es,
               const float* __restrict__ ed, const int* __restrict__ row_ptr,
               const int* __restrict__ col_src, const float* __restrict__ bg,
               float* __restrict__ h, unsigned* __restrict__ hbf2){
  int i = blockIdx.x*4 + (threadIdx.x >> 6);
  if (i >= N_NODES) return;
  int lane = threadIdx.x & 63;
  int start = row_ptr[i], end = row_ptr[i+1];
  float edi = ed[i];
  float m = leaky(es[i] + edi);          // self-loop score
  unsigned us = hp2[(size_t)i*64 + lane];
  float acc0 = bf_lo(us), acc1 = bf_hi(us);   // weight exp(0)=1
  float z = 1.f;
  int j = start;
  for (; j + 4 <= end; j += 4){
    int s0 = col_src[j], s1 = col_src[j+1], s2 = col_src[j+2], s3 = col_src[j+3];
    float e0 = leaky(es[s0]+edi), e1 = leaky(es[s1]+edi);
    float e2 = leaky(es[s2]+edi), e3 = leaky(es[s3]+edi);
    unsigned u0 = hp2[(size_t)s0*64+lane], u1 = hp2[(size_t)s1*64+lane];
    unsigned u2 = hp2[(size_t)s2*64+lane], u3 = hp2[(size_t)s3*64+lane];
    float mn = fmaxf(m, fmaxf(fmaxf(e0,e1), fmaxf(e2,e3)));
    float sc = __expf(m - mn);
    float w0 = __expf(e0-mn), w1 = __expf(e1-mn), w2 = __expf(e2-mn), w3 = __expf(e3-mn);
    z = z*sc + (w0+w1) + (w2+w3);
    acc0 *= sc; acc1 *= sc;
    acc0 = fmaf(w0, bf_lo(u0), acc0); acc1 = fmaf(w0, bf_hi(u0), acc1);
    acc0 = fmaf(w1, bf_lo(u1), acc0); acc1 = fmaf(w1, bf_hi(u1), acc1);
    acc0 = fmaf(w2, bf_lo(u2), acc0); acc1 = fmaf(w2, bf_hi(u2), acc1);
    acc0 = fmaf(w3, bf_lo(u3), acc0); acc1 = fmaf(w3, bf_hi(u3), acc1);
    m = mn;
  }
  for (; j < end; j++){
    int s = col_src[j];
    float e = leaky(es[s]+edi);
    unsigned u = hp2[(size_t)s*64+lane];
    float mn = fmaxf(m, e);
    float sc = __expf(m - mn);
    float w = __expf(e - mn);
    z = z*sc + w;
    acc0 = fmaf(w, bf_lo(u), acc0*sc);
    acc1 = fmaf(w, bf_hi(u), acc1*sc);
    m = mn;
  }
  float inv = 1.f / z;
  float r0 = fmaf(acc0, inv, bg[2*lane]);
  float r1 = fmaf(acc1, inv, bg[2*lane+1]);
  r0 = r0 > 0.f ? r0 : 0.f;
  r1 = r1 > 0.f ? r1 : 0.f;
  size_t o = (size_t)i*128 + 2*lane;
  float2 hv = *(float2*)&h[o];
  hv.x += r0; hv.y += r1;
  *(float2*)&h[o] = hv;
  hbf2[(size_t)i*64 + lane] = f2bf(hv.x) | (f2bf(hv.y)<<16);
}

// ---------------- global_add_pool (batch sorted -> run accumulate) ----------------
__global__ __launch_bounds__(256)
void k_pool(const float* __restrict__ h, const int* __restrict__ batch,
            float* __restrict__ pooled){
  int lane = threadIdx.x & 63, w = threadIdx.x >> 6;
  int n0 = blockIdx.x*128 + w*32;
  if (n0 >= N_NODES) return;
  int nEnd = n0 + 32; if (nEnd > N_NODES) nEnd = N_NODES;
  int cur = batch[n0];
  float a0 = 0.f, a1 = 0.f;
  for (int n = n0; n < nEnd; n++){
    int b = batch[n];
    if (b != cur){
      atomicAdd(&pooled[cur*128 + 2*lane],     a0);
      atomicAdd(&pooled[cur*128 + 2*lane + 1], a1);
      a0 = 0.f; a1 = 0.f; cur = b;
    }
    float2 hv = *(const float2*)&h[(size_t)n*128 + 2*lane];
    a0 += hv.x; a1 += hv.y;
  }
  atomicAdd(&pooled[cur*128 + 2*lane],     a0);
  atomicAdd(&pooled[cur*128 + 2*lane + 1], a1);
}

__global__ void k_final(const float* __restrict__ pooled, const float* __restrict__ W2,
                        const float* __restrict__ b2, float* __restrict__ out){
  int gid = blockIdx.x*256 + threadIdx.x;
  if (gid >= NG*DOUT) return;
  int r = gid >> 6, c = gid & 63;
  float acc = b2[c];
  #pragma unroll 4
  for (int k=0;k<DH;k++) acc = fmaf(pooled[r*DH+k], W2[k*DOUT+c], acc);
  out[(size_t)r*DOUT + c] = acc;
}

extern "C" void kernel_launch(void* const* d_in, const int* in_sizes, int n_in,
                              void* d_out, int out_size, void* d_ws, size_t ws_size,
                              hipStream_t stream){
  const float* x     = (const float*)d_in[0];
  const int*   ei    = (const int*)d_in[1];
  const int*   batch = (const int*)d_in[2];
  const float* W1    = (const float*)d_in[3];
  const float* b1    = (const float*)d_in[4];
  const float* Wg    = (const float*)d_in[5];
  const float* avs   = (const float*)d_in[6];
  const float* avd   = (const float*)d_in[7];
  const float* bgv   = (const float*)d_in[8];
  const float* W2    = (const float*)d_in[9];
  const float* b2    = (const float*)d_in[10];
  float* out = (float*)d_out;

  char* ws = (char*)d_ws;
  float* h        = (float*)ws;                    ws += (size_t)N_NODES*DH*4;   // 25.6 MB
  unsigned short* hbf = (unsigned short*)ws;       ws += (size_t)N_NODES*DH*2;   // 12.8 MB
  unsigned short* hp  = (unsigned short*)ws;       ws += (size_t)N_NODES*DH*2;   // 12.8 MB (aliases xbf)
  unsigned short* xbf = hp;                        // x_bf16 consumed before hp is first written
  float* es       = (float*)ws;                    ws += (size_t)N_NODES*4;
  float* ed       = (float*)ws;                    ws += (size_t)N_NODES*4;
  float* pooled   = (float*)ws;                    ws += NG*DH*4;
  unsigned short* Wt = (unsigned short*)ws;        ws += 4*16384*2;              // bf16 Wt x4
  int* counts     = (int*)ws;                      ws += (size_t)N_NODES*4;
  int* row_ptr    = (int*)ws;                      ws += ((size_t)N_NODES+1)*4;
  int* cursor     = (int*)ws;                      ws += (size_t)N_NODES*4;
  int* col_src    = (int*)ws;                      ws += (size_t)N_EDGES*4;
  int* bsum       = (int*)ws;                      ws += 64*4;
  int* boff       = (int*)ws;                      ws += 64*4;

  const int* esrc = ei;
  const int* edst = ei + N_EDGES;

  hipMemsetAsync(counts, 0, N_NODES*sizeof(int), stream);
  hipMemsetAsync(pooled, 0, NG*DH*sizeof(float), stream);

  k_hist<<<(N_EDGES+255)/256, 256, 0, stream>>>(edst, counts);
  int nb = (N_NODES + 2047)/2048;
  k_bscan1<<<nb,256,0,stream>>>(counts, bsum);
  k_bscan2<<<1,64,0,stream>>>(bsum, boff, row_ptr, nb);
  k_bscan3<<<nb,256,0,stream>>>(counts, boff, row_ptr, cursor);
  k_scatter<<<(N_EDGES+255)/256,256,0,stream>>>(esrc, edst, cursor, col_src);

  k_prep<<<(4*16384+255)/256, 256, 0, stream>>>(W1, Wg, Wt);
  k_cast<<<(N_NODES*32+255)/256, 256, 0, stream>>>(x, (uint2*)xbf);

  int lb = (N_NODES + 63)/64;   // 782 blocks
  // mlp1: h = x@W1 + b1 (fp32 out + bf16 copy)
  k_linear_mfma<<<lb, 256, 0, stream>>>(xbf, Wt, b1, nullptr, nullptr,
                                        h, hbf, nullptr, nullptr, N_NODES);
  for (int l=0; l<3; l++){
    k_linear_mfma<<<lb, 256, 0, stream>>>(hbf, Wt + (size_t)(l+1)*16384, nullptr,
                                          avs + l*DH, avd + l*DH,
                                          nullptr, hp, es, ed, N_NODES);
    k_gat_agg<<<(N_NODES+3)/4, 256, 0, stream>>>((const unsigned*)hp, es, ed,
                                                 row_ptr, col_src, bgv + l*DH,
                                                 h, (unsigned*)hbf);
  }
  k_pool<<<(N_NODES+127)/128, 256, 0, stream>>>(h, batch, pooled);
  k_final<<<(NG*DOUT+255)/256, 256, 0, stream>>>(pooled, W2, b2, out);
}

// Round 3
// 343.157 us; speedup vs baseline: 1.7545x; 1.0363x over previous
//
#include <hip/hip_runtime.h>

#define N_NODES 50000
#define N_EDGES 600000
#define DH 128
#define DOUT 64
#define NG 64
#define SLOPE 0.2f

using short8  = __attribute__((ext_vector_type(8))) short;
using floatx4 = __attribute__((ext_vector_type(4))) float;

__device__ __forceinline__ float leaky(float v){ return v > 0.f ? v : v*SLOPE; }
__device__ __forceinline__ unsigned f2bf(float x){
  unsigned u = __float_as_uint(x);
  return (u + 0x7fffu + ((u>>16)&1u)) >> 16;          // RNE bf16
}
__device__ __forceinline__ float bf_lo(unsigned u){ return __uint_as_float(u<<16); }
__device__ __forceinline__ float bf_hi(unsigned u){ return __uint_as_float(u & 0xffff0000u); }
__device__ __forceinline__ float rl_f(float v, int l){
  return __uint_as_float(__builtin_amdgcn_readlane(__float_as_uint(v), l));
}
__device__ __forceinline__ int rl_i(int v, int l){
  return __builtin_amdgcn_readlane(v, l);
}

// ---------------- CSR build (by dst), self-loops handled implicitly ----------------
__global__ void k_hist(const int* __restrict__ dst, int* __restrict__ counts){
  int e = blockIdx.x*256 + threadIdx.x;
  if (e < N_EDGES) atomicAdd(&counts[dst[e]], 1);
}

__global__ void k_bscan1(const int* __restrict__ counts, int* __restrict__ bsum){
  __shared__ int sb[256];
  int base = blockIdx.x*2048;
  int t = threadIdx.x;
  int s = 0;
  #pragma unroll
  for (int j=0;j<8;j++){ int i = base + t*8 + j; if (i < N_NODES) s += counts[i]; }
  sb[t]=s; __syncthreads();
  for (int off=128; off>0; off>>=1){ if (t<off) sb[t]+=sb[t+off]; __syncthreads(); }
  if (t==0) bsum[blockIdx.x]=sb[0];
}

__global__ void k_bscan2(const int* __restrict__ bsum, int* __restrict__ boff,
                         int* __restrict__ row_ptr, int nb){
  if (threadIdx.x==0 && blockIdx.x==0){
    int run=0;
    for (int b=0;b<nb;b++){ boff[b]=run; run+=bsum[b]; }
    row_ptr[N_NODES]=run;
  }
}

__global__ void k_bscan3(const int* __restrict__ counts, const int* __restrict__ boff,
                         int* __restrict__ row_ptr, int* __restrict__ cursor){
  __shared__ int sb[256];
  int base = blockIdx.x*2048;
  int t = threadIdx.x;
  int c[8]; int s=0;
  #pragma unroll
  for (int j=0;j<8;j++){ int i = base+t*8+j; c[j] = (i<N_NODES)? counts[i]:0; s += c[j]; }
  sb[t]=s; __syncthreads();
  for (int off=1; off<256; off<<=1){
    int v = (t>=off)? sb[t-off] : 0;
    __syncthreads();
    sb[t]+=v;
    __syncthreads();
  }
  int run = sb[t]-s + boff[blockIdx.x];
  #pragma unroll
  for (int j=0;j<8;j++){
    int i = base+t*8+j;
    if (i<N_NODES){ row_ptr[i]=run; cursor[i]=run; run+=c[j]; }
  }
}

__global__ void k_scatter(const int* __restrict__ esrc, const int* __restrict__ edst,
                          int* __restrict__ cursor, int* __restrict__ col_src){
  int e = blockIdx.x*256 + threadIdx.x;
  if (e < N_EDGES){
    int d = edst[e];
    int p = atomicAdd(&cursor[d],1);
    col_src[p] = esrc[e];
  }
}

// ---------------- weight prep: W[k][n] fp32 -> Wt[n][k] bf16, 4 matrices ----------------
__global__ void k_prep(const float* __restrict__ W1, const float* __restrict__ Wg,
                       unsigned short* __restrict__ Wt){
  int idx = blockIdx.x*256 + threadIdx.x;      // 4*16384
  if (idx >= 4*16384) return;
  int mi = idx >> 14, r = idx & 16383;
  int k = r >> 7, n = r & 127;
  const float* src = (mi==0) ? W1 : (Wg + (size_t)(mi-1)*16384);
  float v = src[k*128 + n];
  Wt[(size_t)mi*16384 + (size_t)n*128 + k] = (unsigned short)f2bf(v);
}

// ---------------- MFMA GEMM: [nrows,128] x [128,128] -> out, fused es/ed ----------------
// 512 thr / 8 waves / 128 rows per block. Wt: [n][k] bf16 staged in LDS (+8 pad).
// A frag: A[m=lane&15][k=quad*8+j]; B frag: B[k=quad*8+j][n=lane&15]; C/D: col=lane&15,row=quad*4+reg
template<bool AFP32>
__global__ __launch_bounds__(512)
void k_linear_mfma(const void* __restrict__ Av,
                   const unsigned short* __restrict__ Wt,
                   const float* __restrict__ bias,
                   const float* __restrict__ avs, const float* __restrict__ avd,
                   float* __restrict__ outF, unsigned short* __restrict__ outB,
                   float* __restrict__ es, float* __restrict__ ed, int nrows){
  __shared__ unsigned short wlds[128*136];
  int tid = threadIdx.x;
  #pragma unroll
  for (int i=0;i<4;i++){
    int flat = i*4096 + tid*8;
    int n = flat >> 7, kb = flat & 127;
    *(short8*)&wlds[n*136 + kb] = *(const short8*)(Wt + flat);
  }
  __syncthreads();

  int wid = tid >> 6, lane = tid & 63;
  int l15 = lane & 15, quad = lane >> 4;
  int R0 = blockIdx.x*128 + wid*16;
  int arow = R0 + l15; if (arow >= nrows) arow = nrows-1;

  floatx4 acc[8];
  #pragma unroll
  for (int nt=0;nt<8;nt++){ acc[nt][0]=0.f; acc[nt][1]=0.f; acc[nt][2]=0.f; acc[nt][3]=0.f; }

  #pragma unroll
  for (int k0=0;k0<128;k0+=32){
    short8 a;
    if (AFP32){
      const float* Ap = (const float*)Av + (size_t)arow*128 + quad*8 + k0;
      float4 v0 = *(const float4*)Ap;
      float4 v1 = *(const float4*)(Ap+4);
      a[0]=(short)f2bf(v0.x); a[1]=(short)f2bf(v0.y); a[2]=(short)f2bf(v0.z); a[3]=(short)f2bf(v0.w);
      a[4]=(short)f2bf(v1.x); a[5]=(short)f2bf(v1.y); a[6]=(short)f2bf(v1.z); a[7]=(short)f2bf(v1.w);
    } else {
      a = *(const short8*)((const unsigned short*)Av + (size_t)arow*128 + quad*8 + k0);
    }
    const unsigned short* bp = &wlds[l15*136 + quad*8 + k0];
    #pragma unroll
    for (int nt=0;nt<8;nt++){
      short8 b = *(const short8*)(bp + nt*16*136);
      acc[nt] = __builtin_amdgcn_mfma_f32_16x16x32_bf16(a, b, acc[nt], 0,0,0);
    }
  }

  float bs[8], as[8], ad[8];
  #pragma unroll
  for (int nt=0;nt<8;nt++){
    int c = nt*16 + l15;
    bs[nt] = bias ? bias[c] : 0.f;
    as[nt] = avs ? avs[c] : 0.f;
    ad[nt] = avd ? avd[c] : 0.f;
  }
  #pragma unroll
  for (int reg=0; reg<4; reg++){
    int r = R0 + quad*4 + reg;
    if (r < nrows){
      float ps = 0.f, pd = 0.f;
      #pragma unroll
      for (int nt=0;nt<8;nt++){
        float v = acc[nt][reg] + bs[nt];
        int c = nt*16 + l15;
        if (outF) outF[(size_t)r*128 + c] = v;
        if (outB) outB[(size_t)r*128 + c] = (unsigned short)f2bf(v);
        ps = fmaf(v, as[nt], ps);
        pd = fmaf(v, ad[nt], pd);
      }
      if (es){
        #pragma unroll
        for (int off=1; off<16; off<<=1){
          ps += __shfl_xor(ps, off, 64);
          pd += __shfl_xor(pd, off, 64);
        }
        if (l15==0){ es[r]=ps; ed[r]=pd; }
      }
    }
  }
}

// ---------------- GAT aggregation: wave/node, chunked two-phase softmax ----------------
// Phase 1 (lane-parallel, per 64-edge chunk): e, chunk max, exp, sum via butterfly.
// Phase 2 (serial): readlane-broadcast (src, w) -> coalesced gather + 2 fma/lane.
__global__ __launch_bounds__(256)
void k_gat_agg(const unsigned* __restrict__ hp2, const float* __restrict__ es,
               const float* __restrict__ ed, const int* __restrict__ row_ptr,
               const int* __restrict__ col_src, const float* __restrict__ bg,
               float* __restrict__ h, unsigned* __restrict__ hbf2){
  int i = blockIdx.x*4 + (threadIdx.x >> 6);
  if (i >= N_NODES) return;
  int lane = threadIdx.x & 63;
  int start = row_ptr[i], end = row_ptr[i+1];
  float edi = ed[i];
  float m = leaky(es[i] + edi);               // self-loop score
  unsigned us = hp2[(size_t)i*64 + lane];
  float acc0 = bf_lo(us), acc1 = bf_hi(us);   // self weight exp(0)=1
  float z = 1.f;

  for (int c0 = start; c0 < end; c0 += 64){
    int j = c0 + lane;
    bool valid = j < end;
    int s = valid ? col_src[j] : 0;
    float e = valid ? leaky(es[s] + edi) : -1e30f;
    float cm = e;
    #pragma unroll
    for (int off=32; off>0; off>>=1) cm = fmaxf(cm, __shfl_xor(cm, off, 64));
    float mn = fmaxf(m, cm);
    float sc = __expf(m - mn);
    float w = valid ? __expf(e - mn) : 0.f;
    float zs = w;
    #pragma unroll
    for (int off=32; off>0; off>>=1) zs += __shfl_xor(zs, off, 64);
    z = z*sc + zs;
    acc0 *= sc; acc1 *= sc;
    m = mn;

    int len = end - c0; if (len > 64) len = 64;
    int t = 0;
    for (; t + 4 <= len; t += 4){
      int   s0=rl_i(s,t),   s1=rl_i(s,t+1),   s2=rl_i(s,t+2),   s3=rl_i(s,t+3);
      float w0=rl_f(w,t),   w1=rl_f(w,t+1),   w2=rl_f(w,t+2),   w3=rl_f(w,t+3);
      unsigned u0 = hp2[(size_t)s0*64+lane], u1 = hp2[(size_t)s1*64+lane];
      unsigned u2 = hp2[(size_t)s2*64+lane], u3 = hp2[(size_t)s3*64+lane];
      acc0 = fmaf(w0, bf_lo(u0), acc0); acc1 = fmaf(w0, bf_hi(u0), acc1);
      acc0 = fmaf(w1, bf_lo(u1), acc0); acc1 = fmaf(w1, bf_hi(u1), acc1);
      acc0 = fmaf(w2, bf_lo(u2), acc0); acc1 = fmaf(w2, bf_hi(u2), acc1);
      acc0 = fmaf(w3, bf_lo(u3), acc0); acc1 = fmaf(w3, bf_hi(u3), acc1);
    }
    for (; t < len; t++){
      int   st = rl_i(s,t);
      float wt = rl_f(w,t);
      unsigned u = hp2[(size_t)st*64+lane];
      acc0 = fmaf(wt, bf_lo(u), acc0);
      acc1 = fmaf(wt, bf_hi(u), acc1);
    }
  }

  float inv = 1.f / z;
  float r0 = fmaf(acc0, inv, bg[2*lane]);
  float r1 = fmaf(acc1, inv, bg[2*lane+1]);
  r0 = r0 > 0.f ? r0 : 0.f;
  r1 = r1 > 0.f ? r1 : 0.f;
  size_t o = (size_t)i*128 + 2*lane;
  float2 hv = *(float2*)&h[o];
  hv.x += r0; hv.y += r1;
  *(float2*)&h[o] = hv;
  hbf2[(size_t)i*64 + lane] = f2bf(hv.x) | (f2bf(hv.y)<<16);
}

// ---------------- global_add_pool (batch sorted -> run accumulate) ----------------
__global__ __launch_bounds__(256)
void k_pool(const float* __restrict__ h, const int* __restrict__ batch,
            float* __restrict__ pooled){
  int lane = threadIdx.x & 63, w = threadIdx.x >> 6;
  int n0 = blockIdx.x*128 + w*32;
  if (n0 >= N_NODES) return;
  int nEnd = n0 + 32; if (nEnd > N_NODES) nEnd = N_NODES;
  int cur = batch[n0];
  float a0 = 0.f, a1 = 0.f;
  for (int n = n0; n < nEnd; n++){
    int b = batch[n];
    if (b != cur){
      atomicAdd(&pooled[cur*128 + 2*lane],     a0);
      atomicAdd(&pooled[cur*128 + 2*lane + 1], a1);
      a0 = 0.f; a1 = 0.f; cur = b;
    }
    float2 hv = *(const float2*)&h[(size_t)n*128 + 2*lane];
    a0 += hv.x; a1 += hv.y;
  }
  atomicAdd(&pooled[cur*128 + 2*lane],     a0);
  atomicAdd(&pooled[cur*128 + 2*lane + 1], a1);
}

__global__ void k_final(const float* __restrict__ pooled, const float* __restrict__ W2,
                        const float* __restrict__ b2, float* __restrict__ out){
  int gid = blockIdx.x*256 + threadIdx.x;
  if (gid >= NG*DOUT) return;
  int r = gid >> 6, c = gid & 63;
  float acc = b2[c];
  #pragma unroll 4
  for (int k=0;k<DH;k++) acc = fmaf(pooled[r*DH+k], W2[k*DOUT+c], acc);
  out[(size_t)r*DOUT + c] = acc;
}

extern "C" void kernel_launch(void* const* d_in, const int* in_sizes, int n_in,
                              void* d_out, int out_size, void* d_ws, size_t ws_size,
                              hipStream_t stream){
  const float* x     = (const float*)d_in[0];
  const int*   ei    = (const int*)d_in[1];
  const int*   batch = (const int*)d_in[2];
  const float* W1    = (const float*)d_in[3];
  const float* b1    = (const float*)d_in[4];
  const float* Wg    = (const float*)d_in[5];
  const float* avs   = (const float*)d_in[6];
  const float* avd   = (const float*)d_in[7];
  const float* bgv   = (const float*)d_in[8];
  const float* W2    = (const float*)d_in[9];
  const float* b2    = (const float*)d_in[10];
  float* out = (float*)d_out;

  char* ws = (char*)d_ws;
  float* h        = (float*)ws;                    ws += (size_t)N_NODES*DH*4;
  unsigned short* hbf = (unsigned short*)ws;       ws += (size_t)N_NODES*DH*2;
  unsigned short* hp  = (unsigned short*)ws;       ws += (size_t)N_NODES*DH*2;
  float* es       = (float*)ws;                    ws += (size_t)N_NODES*4;
  float* ed       = (float*)ws;                    ws += (size_t)N_NODES*4;
  float* pooled   = (float*)ws;                    ws += NG*DH*4;
  unsigned short* Wt = (unsigned short*)ws;        ws += 4*16384*2;
  int* counts     = (int*)ws;                      ws += (size_t)N_NODES*4;
  int* row_ptr    = (int*)ws;                      ws += ((size_t)N_NODES+1)*4;
  int* cursor     = (int*)ws;                      ws += (size_t)N_NODES*4;
  int* col_src    = (int*)ws;                      ws += (size_t)N_EDGES*4;
  int* bsum       = (int*)ws;                      ws += 64*4;
  int* boff       = (int*)ws;                      ws += 64*4;

  const int* esrc = ei;
  const int* edst = ei + N_EDGES;

  hipMemsetAsync(counts, 0, N_NODES*sizeof(int), stream);
  hipMemsetAsync(pooled, 0, NG*DH*sizeof(float), stream);

  k_hist<<<(N_EDGES+255)/256, 256, 0, stream>>>(edst, counts);
  int nb = (N_NODES + 2047)/2048;
  k_bscan1<<<nb,256,0,stream>>>(counts, bsum);
  k_bscan2<<<1,64,0,stream>>>(bsum, boff, row_ptr, nb);
  k_bscan3<<<nb,256,0,stream>>>(counts, boff, row_ptr, cursor);
  k_scatter<<<(N_EDGES+255)/256,256,0,stream>>>(esrc, edst, cursor, col_src);

  k_prep<<<(4*16384+255)/256, 256, 0, stream>>>(W1, Wg, Wt);

  int lb = (N_NODES + 127)/128;   // 391 blocks, 512 threads
  k_linear_mfma<true><<<lb, 512, 0, stream>>>(x, Wt, b1, nullptr, nullptr,
                                              h, hbf, nullptr, nullptr, N_NODES);
  for (int l=0; l<3; l++){
    k_linear_mfma<false><<<lb, 512, 0, stream>>>(hbf, Wt + (size_t)(l+1)*16384, nullptr,
                                                 avs + l*DH, avd + l*DH,
                                                 nullptr, hp, es, ed, N_NODES);
    k_gat_agg<<<(N_NODES+3)/4, 256, 0, stream>>>((const unsigned*)hp, es, ed,
                                                 row_ptr, col_src, bgv + l*DH,
                                                 h, (unsigned*)hbf);
  }
  k_pool<<<(N_NODES+127)/128, 256, 0, stream>>>(h, batch, pooled);
  k_final<<<(NG*DOUT+255)/256, 256, 0, stream>>>(pooled, W2, b2, out);
}

// Round 4
// 335.735 us; speedup vs baseline: 1.7933x; 1.0221x over previous
//
#include <hip/hip_runtime.h>

#define N_NODES 50000
#define N_EDGES 600000
#define DH 128
#define DOUT 64
#define NG 64
#define SLOPE 0.2f

using short8  = __attribute__((ext_vector_type(8))) short;
using floatx4 = __attribute__((ext_vector_type(4))) float;

__device__ __forceinline__ float leaky(float v){ return fmaxf(v, SLOPE*v); }
__device__ __forceinline__ unsigned f2bf(float x){
  unsigned u = __float_as_uint(x);
  return (u + 0x7fffu + ((u>>16)&1u)) >> 16;          // RNE bf16
}
#if __has_builtin(__builtin_amdgcn_cvt_pk_bf16_f32)
__device__ __forceinline__ unsigned pack2bf(float a, float b){
  auto t = __builtin_amdgcn_cvt_pk_bf16_f32(a, b);
  unsigned u; __builtin_memcpy(&u, &t, 4); return u;
}
#else
__device__ __forceinline__ unsigned pack2bf(float a, float b){
  return f2bf(a) | (f2bf(b) << 16);
}
#endif
__device__ __forceinline__ float bf_lo(unsigned u){ return __uint_as_float(u<<16); }
__device__ __forceinline__ float bf_hi(unsigned u){ return __uint_as_float(u & 0xffff0000u); }
__device__ __forceinline__ float rl_f(float v, int l){
  return __uint_as_float(__builtin_amdgcn_readlane(__float_as_uint(v), l));
}
__device__ __forceinline__ int rl_i(int v, int l){
  return __builtin_amdgcn_readlane(v, l);
}

// ---------------- CSR build (by dst), self-loops handled implicitly ----------------
__global__ void k_hist(const int* __restrict__ dst, int* __restrict__ counts){
  int e = blockIdx.x*256 + threadIdx.x;
  if (e < N_EDGES) atomicAdd(&counts[dst[e]], 1);
}

__global__ void k_bscan1(const int* __restrict__ counts, int* __restrict__ bsum){
  __shared__ int sb[256];
  int base = blockIdx.x*2048;
  int t = threadIdx.x;
  int s = 0;
  #pragma unroll
  for (int j=0;j<8;j++){ int i = base + t*8 + j; if (i < N_NODES) s += counts[i]; }
  sb[t]=s; __syncthreads();
  for (int off=128; off>0; off>>=1){ if (t<off) sb[t]+=sb[t+off]; __syncthreads(); }
  if (t==0) bsum[blockIdx.x]=sb[0];
}

__global__ void k_bscan2(const int* __restrict__ bsum, int* __restrict__ boff,
                         int* __restrict__ row_ptr, int nb){
  if (threadIdx.x==0 && blockIdx.x==0){
    int run=0;
    for (int b=0;b<nb;b++){ boff[b]=run; run+=bsum[b]; }
    row_ptr[N_NODES]=run;
  }
}

__global__ void k_bscan3(const int* __restrict__ counts, const int* __restrict__ boff,
                         int* __restrict__ row_ptr, int* __restrict__ cursor){
  __shared__ int sb[256];
  int base = blockIdx.x*2048;
  int t = threadIdx.x;
  int c[8]; int s=0;
  #pragma unroll
  for (int j=0;j<8;j++){ int i = base+t*8+j; c[j] = (i<N_NODES)? counts[i]:0; s += c[j]; }
  sb[t]=s; __syncthreads();
  for (int off=1; off<256; off<<=1){
    int v = (t>=off)? sb[t-off] : 0;
    __syncthreads();
    sb[t]+=v;
    __syncthreads();
  }
  int run = sb[t]-s + boff[blockIdx.x];
  #pragma unroll
  for (int j=0;j<8;j++){
    int i = base+t*8+j;
    if (i<N_NODES){ row_ptr[i]=run; cursor[i]=run; run+=c[j]; }
  }
}

__global__ void k_scatter(const int* __restrict__ esrc, const int* __restrict__ edst,
                          int* __restrict__ cursor, int* __restrict__ col_src){
  int e = blockIdx.x*256 + threadIdx.x;
  if (e < N_EDGES){
    int d = edst[e];
    int p = atomicAdd(&cursor[d],1);
    col_src[p] = esrc[e];
  }
}

// ---------------- weight prep: W[k][n] fp32 -> Wt[n][k] bf16, 4 matrices ----------------
__global__ void k_prep(const float* __restrict__ W1, const float* __restrict__ Wg,
                       unsigned short* __restrict__ Wt){
  int idx = blockIdx.x*256 + threadIdx.x;      // 4*16384
  if (idx >= 4*16384) return;
  int mi = idx >> 14, r = idx & 16383;
  int k = r >> 7, n = r & 127;
  const float* src = (mi==0) ? W1 : (Wg + (size_t)(mi-1)*16384);
  float v = src[k*128 + n];
  Wt[(size_t)mi*16384 + (size_t)n*128 + k] = (unsigned short)f2bf(v);
}

// ---------------- MFMA GEMM (transposed D): out[node][feat], bf16 everywhere ----------
// 512 thr / 8 waves / 128 nodes per block. Wt: [n][k] bf16 staged in LDS (+8 pad).
// mfma(A=Wt frag, B=node frag): D[m=feature][n=node]; C/D: col(node)=lane&15,
// row(feature)=quad*4+reg -> each lane owns 4 CONSECUTIVE features per nt tile.
template<bool AFP32>
__global__ __launch_bounds__(512)
void k_linear_mfma(const void* __restrict__ Av,
                   const unsigned short* __restrict__ Wt,
                   const float* __restrict__ bias,
                   const float* __restrict__ avs, const float* __restrict__ avd,
                   unsigned short* __restrict__ outB,
                   float* __restrict__ es, float* __restrict__ ed, int nrows){
  __shared__ unsigned short wlds[128*136];
  int tid = threadIdx.x;
  #pragma unroll
  for (int i=0;i<4;i++){
    int flat = i*4096 + tid*8;
    int n = flat >> 7, kb = flat & 127;
    *(short8*)&wlds[n*136 + kb] = *(const short8*)(Wt + flat);
  }
  __syncthreads();

  int wid = tid >> 6, lane = tid & 63;
  int l15 = lane & 15, quad = lane >> 4;
  int R0 = blockIdx.x*128 + wid*16;
  int node = R0 + l15;
  int arow = node < nrows ? node : nrows-1;

  floatx4 acc[8];
  #pragma unroll
  for (int nt=0;nt<8;nt++){ acc[nt][0]=0.f; acc[nt][1]=0.f; acc[nt][2]=0.f; acc[nt][3]=0.f; }

  #pragma unroll
  for (int k0=0;k0<128;k0+=32){
    short8 a;                                   // node fragment (B operand)
    if (AFP32){
      const float* Ap = (const float*)Av + (size_t)arow*128 + quad*8 + k0;
      float4 v0 = *(const float4*)Ap;
      float4 v1 = *(const float4*)(Ap+4);
      union { short8 s; unsigned u[4]; } cv;
      cv.u[0]=pack2bf(v0.x,v0.y); cv.u[1]=pack2bf(v0.z,v0.w);
      cv.u[2]=pack2bf(v1.x,v1.y); cv.u[3]=pack2bf(v1.z,v1.w);
      a = cv.s;
    } else {
      a = *(const short8*)((const unsigned short*)Av + (size_t)arow*128 + quad*8 + k0);
    }
    const unsigned short* bp = &wlds[l15*136 + quad*8 + k0];
    #pragma unroll
    for (int nt=0;nt<8;nt++){
      short8 b = *(const short8*)(bp + nt*16*136);   // Wt fragment (A operand)
      acc[nt] = __builtin_amdgcn_mfma_f32_16x16x32_bf16(b, a, acc[nt], 0,0,0);
    }
  }

  bool nv = node < nrows;
  float ps = 0.f, pd = 0.f;
  #pragma unroll
  for (int nt=0;nt<8;nt++){
    int f0 = nt*16 + quad*4;                  // 4 consecutive features for this lane
    float4 bb = make_float4(0.f,0.f,0.f,0.f);
    if (bias) bb = *(const float4*)(bias + f0);
    float v0 = acc[nt][0]+bb.x, v1 = acc[nt][1]+bb.y;
    float v2 = acc[nt][2]+bb.z, v3 = acc[nt][3]+bb.w;
    if (es){
      float4 a4 = *(const float4*)(avs + f0);
      float4 d4 = *(const float4*)(avd + f0);
      ps = fmaf(v0,a4.x, fmaf(v1,a4.y, fmaf(v2,a4.z, fmaf(v3,a4.w, ps))));
      pd = fmaf(v0,d4.x, fmaf(v1,d4.y, fmaf(v2,d4.z, fmaf(v3,d4.w, pd))));
    }
    if (nv){
      uint2 pk; pk.x = pack2bf(v0,v1); pk.y = pack2bf(v2,v3);
      *(uint2*)(outB + (size_t)node*128 + f0) = pk;
    }
  }
  if (es){
    ps += __shfl_xor(ps, 16, 64); ps += __shfl_xor(ps, 32, 64);
    pd += __shfl_xor(pd, 16, 64); pd += __shfl_xor(pd, 32, 64);
    if (quad==0 && nv){ es[node]=ps; ed[node]=pd; }
  }
}

// ---------------- GAT aggregation: wave/node, self-centered softmax (no max pass) -------
// w = exp(e - m0) with m0 = self score (wave-uniform, free). Scores are O(10) dot
// products -> no fp32 overflow risk. Phase 1 lane-parallel w; phase 2 readlane
// broadcast + coalesced scalar-base gather + 2 fma. Residual stream hbf is bf16.
__global__ __launch_bounds__(256)
void k_gat_agg(const unsigned* __restrict__ hp2, const float* __restrict__ es,
               const float* __restrict__ ed, const int* __restrict__ row_ptr,
               const int* __restrict__ col_src, const float* __restrict__ bg,
               unsigned* __restrict__ hbf2){
  int i = blockIdx.x*4 + (threadIdx.x >> 6);
  if (i >= N_NODES) return;
  int lane = threadIdx.x & 63;
  int start = row_ptr[i], end = row_ptr[i+1];
  float edi = ed[i];
  float m0 = leaky(es[i] + edi);              // self score: softmax recentering
  unsigned us = hp2[(size_t)i*64 + lane];
  float acc0 = bf_lo(us), acc1 = bf_hi(us);   // self weight exp(0)=1
  float zl = (lane==0) ? 1.f : 0.f;

  for (int c0 = start; c0 < end; c0 += 64){
    int j = c0 + lane;
    bool valid = j < end;
    int s = valid ? col_src[j] : 0;
    float e = leaky(es[s] + edi);
    float w = valid ? __expf(e - m0) : 0.f;
    zl += w;
    int len = end - c0; if (len > 64) len = 64;
    int t = 0;
    for (; t + 4 <= len; t += 4){
      int   s0=rl_i(s,t),   s1=rl_i(s,t+1),   s2=rl_i(s,t+2),   s3=rl_i(s,t+3);
      float w0=rl_f(w,t),   w1=rl_f(w,t+1),   w2=rl_f(w,t+2),   w3=rl_f(w,t+3);
      const unsigned* p0 = hp2 + (size_t)s0*64;
      const unsigned* p1 = hp2 + (size_t)s1*64;
      const unsigned* p2 = hp2 + (size_t)s2*64;
      const unsigned* p3 = hp2 + (size_t)s3*64;
      unsigned u0 = p0[lane], u1 = p1[lane], u2 = p2[lane], u3 = p3[lane];
      acc0 = fmaf(w0, bf_lo(u0), acc0); acc1 = fmaf(w0, bf_hi(u0), acc1);
      acc0 = fmaf(w1, bf_lo(u1), acc0); acc1 = fmaf(w1, bf_hi(u1), acc1);
      acc0 = fmaf(w2, bf_lo(u2), acc0); acc1 = fmaf(w2, bf_hi(u2), acc1);
      acc0 = fmaf(w3, bf_lo(u3), acc0); acc1 = fmaf(w3, bf_hi(u3), acc1);
    }
    for (; t < len; t++){
      int   st = rl_i(s,t);
      float wt = rl_f(w,t);
      unsigned u = (hp2 + (size_t)st*64)[lane];
      acc0 = fmaf(wt, bf_lo(u), acc0);
      acc1 = fmaf(wt, bf_hi(u), acc1);
    }
  }

  float z = zl;
  #pragma unroll
  for (int off=32; off>0; off>>=1) z += __shfl_xor(z, off, 64);
  float inv = 1.f / z;
  float2 bgv = *(const float2*)&bg[2*lane];
  float r0 = fmaf(acc0, inv, bgv.x);
  float r1 = fmaf(acc1, inv, bgv.y);
  r0 = r0 > 0.f ? r0 : 0.f;
  r1 = r1 > 0.f ? r1 : 0.f;
  unsigned ho = hbf2[(size_t)i*64 + lane];    // residual (bf16 stream)
  hbf2[(size_t)i*64 + lane] = pack2bf(r0 + bf_lo(ho), r1 + bf_hi(ho));
}

// ---------------- global_add_pool (batch sorted -> run accumulate), bf16 in ------------
__global__ __launch_bounds__(256)
void k_pool(const unsigned* __restrict__ hbf2, const int* __restrict__ batch,
            float* __restrict__ pooled){
  int lane = threadIdx.x & 63, w = threadIdx.x >> 6;
  int n0 = blockIdx.x*128 + w*32;
  if (n0 >= N_NODES) return;
  int nEnd = n0 + 32; if (nEnd > N_NODES) nEnd = N_NODES;
  int cur = batch[n0];
  float a0 = 0.f, a1 = 0.f;
  for (int n = n0; n < nEnd; n++){
    int b = batch[n];
    if (b != cur){
      atomicAdd(&pooled[cur*128 + 2*lane],     a0);
      atomicAdd(&pooled[cur*128 + 2*lane + 1], a1);
      a0 = 0.f; a1 = 0.f; cur = b;
    }
    unsigned u = hbf2[(size_t)n*64 + lane];
    a0 += bf_lo(u); a1 += bf_hi(u);
  }
  atomicAdd(&pooled[cur*128 + 2*lane],     a0);
  atomicAdd(&pooled[cur*128 + 2*lane + 1], a1);
}

__global__ void k_final(const float* __restrict__ pooled, const float* __restrict__ W2,
                        const float* __restrict__ b2, float* __restrict__ out){
  int gid = blockIdx.x*256 + threadIdx.x;
  if (gid >= NG*DOUT) return;
  int r = gid >> 6, c = gid & 63;
  float acc = b2[c];
  #pragma unroll 4
  for (int k=0;k<DH;k++) acc = fmaf(pooled[r*DH+k], W2[k*DOUT+c], acc);
  out[(size_t)r*DOUT + c] = acc;
}

extern "C" void kernel_launch(void* const* d_in, const int* in_sizes, int n_in,
                              void* d_out, int out_size, void* d_ws, size_t ws_size,
                              hipStream_t stream){
  const float* x     = (const float*)d_in[0];
  const int*   ei    = (const int*)d_in[1];
  const int*   batch = (const int*)d_in[2];
  const float* W1    = (const float*)d_in[3];
  const float* b1    = (const float*)d_in[4];
  const float* Wg    = (const float*)d_in[5];
  const float* avs   = (const float*)d_in[6];
  const float* avd   = (const float*)d_in[7];
  const float* bgv   = (const float*)d_in[8];
  const float* W2    = (const float*)d_in[9];
  const float* b2    = (const float*)d_in[10];
  float* out = (float*)d_out;

  char* ws = (char*)d_ws;
  unsigned short* hbf = (unsigned short*)ws;       ws += (size_t)N_NODES*DH*2;   // residual stream (bf16)
  unsigned short* hp  = (unsigned short*)ws;       ws += (size_t)N_NODES*DH*2;   // GEMM out (bf16)
  float* es       = (float*)ws;                    ws += (size_t)N_NODES*4;
  float* ed       = (float*)ws;                    ws += (size_t)N_NODES*4;
  float* pooled   = (float*)ws;                    ws += NG*DH*4;
  unsigned short* Wt = (unsigned short*)ws;        ws += 4*16384*2;
  int* counts     = (int*)ws;                      ws += (size_t)N_NODES*4;
  int* row_ptr    = (int*)ws;                      ws += ((size_t)N_NODES+1)*4;
  int* cursor     = (int*)ws;                      ws += (size_t)N_NODES*4;
  int* col_src    = (int*)ws;                      ws += (size_t)N_EDGES*4;
  int* bsum       = (int*)ws;                      ws += 64*4;
  int* boff       = (int*)ws;                      ws += 64*4;

  const int* esrc = ei;
  const int* edst = ei + N_EDGES;

  hipMemsetAsync(counts, 0, N_NODES*sizeof(int), stream);
  hipMemsetAsync(pooled, 0, NG*DH*sizeof(float), stream);

  k_hist<<<(N_EDGES+255)/256, 256, 0, stream>>>(edst, counts);
  int nb = (N_NODES + 2047)/2048;
  k_bscan1<<<nb,256,0,stream>>>(counts, bsum);
  k_bscan2<<<1,64,0,stream>>>(bsum, boff, row_ptr, nb);
  k_bscan3<<<nb,256,0,stream>>>(counts, boff, row_ptr, cursor);
  k_scatter<<<(N_EDGES+255)/256,256,0,stream>>>(esrc, edst, cursor, col_src);

  k_prep<<<(4*16384+255)/256, 256, 0, stream>>>(W1, Wg, Wt);

  int lb = (N_NODES + 127)/128;   // 391 blocks, 512 threads
  k_linear_mfma<true><<<lb, 512, 0, stream>>>(x, Wt, b1, nullptr, nullptr,
                                              hbf, nullptr, nullptr, N_NODES);
  for (int l=0; l<3; l++){
    k_linear_mfma<false><<<lb, 512, 0, stream>>>(hbf, Wt + (size_t)(l+1)*16384, nullptr,
                                                 avs + l*DH, avd + l*DH,
                                                 hp, es, ed, N_NODES);
    k_gat_agg<<<(N_NODES+3)/4, 256, 0, stream>>>((const unsigned*)hp, es, ed,
                                                 row_ptr, col_src, bgv + l*DH,
                                                 (unsigned*)hbf);
  }
  k_pool<<<(N_NODES+127)/128, 256, 0, stream>>>((const unsigned*)hbf, batch, pooled);
  k_final<<<(NG*DOUT+255)/256, 256, 0, stream>>>(pooled, W2, b2, out);
}